// Round 1
// baseline (566.574 us; speedup 1.0000x reference)
//
#include <hip/hip_runtime.h>
#include <math.h>

#define IN_DIM 256
#define HID 64
#define NC 32
#define NEG 0.01f
#define INF_NEG -1e30f

static inline int ceil_div(int a, int b){ return (a + b - 1) / b; }

static __device__ __forceinline__ float lrelu(float x){ return x > 0.f ? x : NEG * x; }

// ---------------- CSR build ----------------

__global__ void hist_kernel(const int* __restrict__ src, int* __restrict__ counts, int E){
  int i = blockIdx.x * blockDim.x + threadIdx.x;
  if (i < E) atomicAdd(&counts[src[i]], 1);
}

// 256 threads x 4 elems = 1024 elems/block. Writes per-element exclusive-within-block.
__global__ void scan_blocks_kernel(const int* __restrict__ counts, int* __restrict__ excl,
                                   int* __restrict__ bsums, int n){
  __shared__ int sh[256];
  int tid = threadIdx.x;
  int base = blockIdx.x * 1024 + tid * 4;
  int c[4]; int tsum = 0;
  #pragma unroll
  for (int j = 0; j < 4; j++){ int i = base + j; c[j] = (i < n) ? counts[i] : 0; tsum += c[j]; }
  sh[tid] = tsum; __syncthreads();
  int val = tsum;
  for (int off = 1; off < 256; off <<= 1){
    int add = (tid >= off) ? sh[tid - off] : 0;
    __syncthreads();
    val += add; sh[tid] = val;
    __syncthreads();
  }
  int p = val - tsum;  // exclusive prefix of this thread within block
  #pragma unroll
  for (int j = 0; j < 4; j++){ int i = base + j; if (i < n) excl[i] = p; p += c[j]; }
  if (tid == 255) bsums[blockIdx.x] = val;
}

// single block; nb <= 256. Exclusive-scans block sums in place; writes row_ptr[n]=E.
__global__ void scan_sums_kernel(int* __restrict__ bsums, int* __restrict__ row_ptr,
                                 int nb, int n, int E){
  __shared__ int sh[256];
  int tid = threadIdx.x;
  int v = (tid < nb) ? bsums[tid] : 0;
  sh[tid] = v; __syncthreads();
  int val = v;
  for (int off = 1; off < 256; off <<= 1){
    int add = (tid >= off) ? sh[tid - off] : 0;
    __syncthreads();
    val += add; sh[tid] = val;
    __syncthreads();
  }
  if (tid < nb) bsums[tid] = val - v;
  if (tid == 0) row_ptr[n] = E;
}

__global__ void add_offsets_kernel(int* __restrict__ excl, const int* __restrict__ bsums, int n){
  int i = blockIdx.x * 1024 + threadIdx.x;
  if (i < n) excl[i] += bsums[blockIdx.x];
}

__global__ void scatter_kernel(const int* __restrict__ src, const int* __restrict__ dst,
                               const int* __restrict__ row_ptr, int* __restrict__ fill,
                               int* __restrict__ csr, int E){
  int i = blockIdx.x * blockDim.x + threadIdx.x;
  if (i >= E) return;
  int s = src[i];
  int pos = row_ptr[s] + atomicAdd(&fill[s], 1);
  csr[pos] = dst[i];
}

// ---------------- GEMM 1: X[N,256] @ W1[256,64], epilogue: H row + s/d scores ----------------

__global__ __launch_bounds__(256) void gemm1_kernel(const float* __restrict__ X, const float* __restrict__ W,
      const float* __restrict__ a, float* __restrict__ H,
      float* __restrict__ svec, float* __restrict__ dvec, int n){
  __shared__ float xs[32 * 257];   // [k_local][row], stride 257 breaks bank conflicts
  int tid = threadIdx.x;
  int r0 = blockIdx.x * 256;
  int r = r0 + tid;
  float acc[64];
  #pragma unroll
  for (int c = 0; c < 64; c++) acc[c] = 0.f;
  int f = tid & 7, rl = tid >> 3;
  for (int kb = 0; kb < 8; kb++){
    __syncthreads();
    // stage 256 rows x 32 cols; 8 threads per row, one float4 each, 8 passes
    #pragma unroll
    for (int p = 0; p < 8; p++){
      int row = p * 32 + rl;
      int gr = r0 + row;
      float4 v = make_float4(0.f, 0.f, 0.f, 0.f);
      if (gr < n) v = *(const float4*)(X + (size_t)gr * IN_DIM + kb * 32 + f * 4);
      xs[(f * 4 + 0) * 257 + row] = v.x;
      xs[(f * 4 + 1) * 257 + row] = v.y;
      xs[(f * 4 + 2) * 257 + row] = v.z;
      xs[(f * 4 + 3) * 257 + row] = v.w;
    }
    __syncthreads();
    #pragma unroll 2
    for (int k = 0; k < 32; k++){
      float x = xs[k * 257 + tid];
      const float* wr = W + (size_t)(kb * 32 + k) * 64;   // wave-uniform -> s_load
      #pragma unroll
      for (int c = 0; c < 64; c++) acc[c] = fmaf(x, wr[c], acc[c]);
    }
  }
  if (r < n){
    float s = 0.f, d = 0.f;
    #pragma unroll
    for (int c = 0; c < 64; c++){ s = fmaf(acc[c], a[c], s); d = fmaf(acc[c], a[64 + c], d); }
    svec[r] = s; dvec[r] = d;
    float* Hr = H + (size_t)r * 64;
    #pragma unroll
    for (int j = 0; j < 16; j++)
      *(float4*)(Hr + 4 * j) = make_float4(acc[4*j], acc[4*j+1], acc[4*j+2], acc[4*j+3]);
  }
}

// ---------------- GEMM 2: hid[N,64] @ W2[64,32], epilogue: H2 row + s/d scores ----------------

__global__ __launch_bounds__(256) void gemm2_kernel(const float* __restrict__ X, const float* __restrict__ W,
      const float* __restrict__ a, float* __restrict__ H,
      float* __restrict__ svec, float* __restrict__ dvec, int n){
  __shared__ float xs[32 * 257];
  int tid = threadIdx.x;
  int r0 = blockIdx.x * 256;
  int r = r0 + tid;
  float acc[32];
  #pragma unroll
  for (int c = 0; c < 32; c++) acc[c] = 0.f;
  int f = tid & 7, rl = tid >> 3;
  for (int kb = 0; kb < 2; kb++){
    __syncthreads();
    #pragma unroll
    for (int p = 0; p < 8; p++){
      int row = p * 32 + rl;
      int gr = r0 + row;
      float4 v = make_float4(0.f, 0.f, 0.f, 0.f);
      if (gr < n) v = *(const float4*)(X + (size_t)gr * 64 + kb * 32 + f * 4);
      xs[(f * 4 + 0) * 257 + row] = v.x;
      xs[(f * 4 + 1) * 257 + row] = v.y;
      xs[(f * 4 + 2) * 257 + row] = v.z;
      xs[(f * 4 + 3) * 257 + row] = v.w;
    }
    __syncthreads();
    #pragma unroll 2
    for (int k = 0; k < 32; k++){
      float x = xs[k * 257 + tid];
      const float* wr = W + (size_t)(kb * 32 + k) * 32;
      #pragma unroll
      for (int c = 0; c < 32; c++) acc[c] = fmaf(x, wr[c], acc[c]);
    }
  }
  if (r < n){
    float s = 0.f, d = 0.f;
    #pragma unroll
    for (int c = 0; c < 32; c++){ s = fmaf(acc[c], a[c], s); d = fmaf(acc[c], a[32 + c], d); }
    svec[r] = s; dvec[r] = d;
    float* Hr = H + (size_t)r * 32;
    #pragma unroll
    for (int j = 0; j < 8; j++)
      *(float4*)(Hr + 4 * j) = make_float4(acc[4*j], acc[4*j+1], acc[4*j+2], acc[4*j+3]);
  }
}

// ---------------- Aggregate layer 1: online softmax + ELU, D=64, 16 lanes/node ----------------

__global__ __launch_bounds__(256) void agg1_kernel(const float* __restrict__ H, const float* __restrict__ sv,
      const float* __restrict__ dv, const int* __restrict__ row_ptr, const int* __restrict__ csr,
      float* __restrict__ out, int n){
  int t = blockIdx.x * 256 + threadIdx.x;
  int g = t >> 4, lane = t & 15;
  if (g >= n) return;
  int beg = row_ptr[g], end = row_ptr[g + 1];
  float si = sv[g];
  float m = INF_NEG, l = 0.f;
  float ox = 0.f, oy = 0.f, oz = 0.f, ow = 0.f;
  for (int e = beg; e < end; e++){
    int dd = csr[e];
    float ev = lrelu(si + dv[dd]);
    float mn = fmaxf(m, ev);
    float al = __expf(m - mn);
    float w  = __expf(ev - mn);
    float4 v = *(const float4*)(H + (size_t)dd * 64 + lane * 4);
    ox = ox * al + w * v.x; oy = oy * al + w * v.y;
    oz = oz * al + w * v.z; ow = ow * al + w * v.w;
    l = l * al + w;
    m = mn;
  }
  float inv = (l > 0.f) ? 1.f / l : 0.f;
  ox *= inv; oy *= inv; oz *= inv; ow *= inv;
  ox = ox > 0.f ? ox : __expf(ox) - 1.f;
  oy = oy > 0.f ? oy : __expf(oy) - 1.f;
  oz = oz > 0.f ? oz : __expf(oz) - 1.f;
  ow = ow > 0.f ? ow : __expf(ow) - 1.f;
  *(float4*)(out + (size_t)g * 64 + lane * 4) = make_float4(ox, oy, oz, ow);
}

// ---------------- Aggregate layer 2: online softmax + log_softmax, D=32, 8 lanes/node ----------------

__global__ __launch_bounds__(256) void agg2_kernel(const float* __restrict__ H, const float* __restrict__ sv,
      const float* __restrict__ dv, const int* __restrict__ row_ptr, const int* __restrict__ csr,
      float* __restrict__ out, int n){
  int t = blockIdx.x * 256 + threadIdx.x;
  int g = t >> 3, lane = t & 7;
  if (g >= n) return;
  int beg = row_ptr[g], end = row_ptr[g + 1];
  float si = sv[g];
  float m = INF_NEG, l = 0.f;
  float ox = 0.f, oy = 0.f, oz = 0.f, ow = 0.f;
  for (int e = beg; e < end; e++){
    int dd = csr[e];
    float ev = lrelu(si + dv[dd]);
    float mn = fmaxf(m, ev);
    float al = __expf(m - mn);
    float w  = __expf(ev - mn);
    float4 v = *(const float4*)(H + (size_t)dd * 32 + lane * 4);
    ox = ox * al + w * v.x; oy = oy * al + w * v.y;
    oz = oz * al + w * v.z; ow = ow * al + w * v.w;
    l = l * al + w;
    m = mn;
  }
  float inv = (l > 0.f) ? 1.f / l : 0.f;
  ox *= inv; oy *= inv; oz *= inv; ow *= inv;
  // log_softmax across the 32 values held by this 8-lane group
  float tm = fmaxf(fmaxf(ox, oy), fmaxf(oz, ow));
  #pragma unroll
  for (int off = 1; off < 8; off <<= 1) tm = fmaxf(tm, __shfl_xor(tm, off, 8));
  float se = __expf(ox - tm) + __expf(oy - tm) + __expf(oz - tm) + __expf(ow - tm);
  #pragma unroll
  for (int off = 1; off < 8; off <<= 1) se += __shfl_xor(se, off, 8);
  float lg = tm + __logf(se);
  *(float4*)(out + (size_t)g * 32 + lane * 4) = make_float4(ox - lg, oy - lg, oz - lg, ow - lg);
}

// ---------------- launch ----------------

extern "C" void kernel_launch(void* const* d_in, const int* in_sizes, int n_in,
                              void* d_out, int out_size, void* d_ws, size_t ws_size,
                              hipStream_t stream) {
  (void)n_in; (void)out_size; (void)ws_size;
  const float* X  = (const float*)d_in[0];
  const int*   EI = (const int*)d_in[1];
  const float* W1 = (const float*)d_in[2];
  const float* W2 = (const float*)d_in[3];
  const float* A1 = (const float*)d_in[4];
  const float* A2 = (const float*)d_in[5];
  float* out = (float*)d_out;

  int N = in_sizes[0] / IN_DIM;
  int E = in_sizes[1] / 2;
  const int* src = EI;
  const int* dst = EI + E;

  auto align_up = [](size_t x){ return (x + 511) & ~(size_t)511; };
  char* w = (char*)d_ws;
  int* counts  = (int*)w;   w += align_up((size_t)N * 4);
  int* fill    = (int*)w;   w += align_up((size_t)N * 4);
  int* row_ptr = (int*)w;   w += align_up((size_t)(N + 1) * 4);
  int* bsums   = (int*)w;   w += align_up(1024);
  int* csr     = (int*)w;   w += align_up((size_t)E * 4);
  float* H1    = (float*)w; w += align_up((size_t)N * 64 * 4);
  float* hid   = (float*)w; w += align_up((size_t)N * 64 * 4);
  float* s1    = (float*)w; w += align_up((size_t)N * 4);
  float* d1    = (float*)w; w += align_up((size_t)N * 4);
  float* s2    = (float*)w; w += align_up((size_t)N * 4);
  float* d2    = (float*)w; w += align_up((size_t)N * 4);
  float* H2    = H1;  // H1 dead after agg1; reuse for layer-2 features

  hipMemsetAsync(counts, 0, (size_t)N * 4, stream);
  hipMemsetAsync(fill,   0, (size_t)N * 4, stream);

  int nb = ceil_div(N, 1024);
  hist_kernel<<<ceil_div(E, 256), 256, 0, stream>>>(src, counts, E);
  scan_blocks_kernel<<<nb, 256, 0, stream>>>(counts, row_ptr, bsums, N);
  scan_sums_kernel<<<1, 256, 0, stream>>>(bsums, row_ptr, nb, N, E);
  add_offsets_kernel<<<nb, 1024, 0, stream>>>(row_ptr, bsums, N);
  scatter_kernel<<<ceil_div(E, 256), 256, 0, stream>>>(src, dst, row_ptr, fill, csr, E);

  gemm1_kernel<<<ceil_div(N, 256), 256, 0, stream>>>(X, W1, A1, H1, s1, d1, N);
  agg1_kernel<<<ceil_div(N * 16, 256), 256, 0, stream>>>(H1, s1, d1, row_ptr, csr, hid, N);
  gemm2_kernel<<<ceil_div(N, 256), 256, 0, stream>>>(hid, W2, A2, H2, s2, d2, N);
  agg2_kernel<<<ceil_div(N * 8, 256), 256, 0, stream>>>(H2, s2, d2, row_ptr, csr, out, N);
}

// Round 2
// 475.013 us; speedup vs baseline: 1.1928x; 1.1928x over previous
//
#include <hip/hip_runtime.h>
#include <math.h>

#define IN_DIM 256
#define HID 64
#define NC 32
#define NEG 0.01f
#define INF_NEG -1e30f
#define SX 68   // LDS stride for transposed X tile (float4-aligned, 2-way conflicts only)

static inline int ceil_div(int a, int b){ return (a + b - 1) / b; }

static __device__ __forceinline__ float lrelu(float x){ return x > 0.f ? x : NEG * x; }

// ---------------- CSR build ----------------

__global__ void hist_kernel(const int* __restrict__ src, int* __restrict__ counts, int E){
  int i = blockIdx.x * blockDim.x + threadIdx.x;
  if (i < E) atomicAdd(&counts[src[i]], 1);
}

__global__ void scan_blocks_kernel(const int* __restrict__ counts, int* __restrict__ excl,
                                   int* __restrict__ bsums, int n){
  __shared__ int sh[256];
  int tid = threadIdx.x;
  int base = blockIdx.x * 1024 + tid * 4;
  int c[4]; int tsum = 0;
  #pragma unroll
  for (int j = 0; j < 4; j++){ int i = base + j; c[j] = (i < n) ? counts[i] : 0; tsum += c[j]; }
  sh[tid] = tsum; __syncthreads();
  int val = tsum;
  for (int off = 1; off < 256; off <<= 1){
    int add = (tid >= off) ? sh[tid - off] : 0;
    __syncthreads();
    val += add; sh[tid] = val;
    __syncthreads();
  }
  int p = val - tsum;
  #pragma unroll
  for (int j = 0; j < 4; j++){ int i = base + j; if (i < n) excl[i] = p; p += c[j]; }
  if (tid == 255) bsums[blockIdx.x] = val;
}

__global__ void scan_sums_kernel(int* __restrict__ bsums, int* __restrict__ row_ptr,
                                 int nb, int n, int E){
  __shared__ int sh[256];
  int tid = threadIdx.x;
  int v = (tid < nb) ? bsums[tid] : 0;
  sh[tid] = v; __syncthreads();
  int val = v;
  for (int off = 1; off < 256; off <<= 1){
    int add = (tid >= off) ? sh[tid - off] : 0;
    __syncthreads();
    val += add; sh[tid] = val;
    __syncthreads();
  }
  if (tid < nb) bsums[tid] = val - v;
  if (tid == 0) row_ptr[n] = E;
}

__global__ void add_offsets_kernel(int* __restrict__ excl, const int* __restrict__ bsums, int n){
  int i = blockIdx.x * 1024 + threadIdx.x;
  if (i < n) excl[i] += bsums[blockIdx.x];
}

__global__ void scatter_kernel(const int* __restrict__ src, const int* __restrict__ dst,
                               const int* __restrict__ row_ptr, int* __restrict__ fill,
                               int* __restrict__ csr, int E){
  int i = blockIdx.x * blockDim.x + threadIdx.x;
  if (i >= E) return;
  int s = src[i];
  int pos = row_ptr[s] + atomicAdd(&fill[s], 1);
  csr[pos] = dst[i];
}

// ---------------- GEMM 1: X[N,256] @ W1[256,64] -> H, s, d ----------------
// Outer-product tiling: block = 64 rows x 64 cols, thread owns 4x4.
// tr = tid>>4 -> rows tr*4..+3 ; tc = tid&15 -> cols tc*4..+3 (row-mates = one 16-lane segment)

__global__ __launch_bounds__(256) void gemm1_kernel(const float* __restrict__ X, const float* __restrict__ W,
      const float* __restrict__ a, float* __restrict__ H,
      float* __restrict__ svec, float* __restrict__ dvec, int n){
  __shared__ float xs[64 * SX];   // [k][row] transposed
  __shared__ float ws[64 * 64];   // [k][col]
  int tid = threadIdx.x;
  int r0 = blockIdx.x * 64;
  int tr = tid >> 4;
  int tc = tid & 15;
  float acc[4][4];
  #pragma unroll
  for (int i = 0; i < 4; i++)
    #pragma unroll
    for (int j = 0; j < 4; j++) acc[i][j] = 0.f;

  for (int kb = 0; kb < 4; kb++){
    __syncthreads();
    // stage X tile 64 rows x 64 k, transposed into xs[k][row]
    #pragma unroll
    for (int p = 0; p < 4; p++){
      int idx = p * 256 + tid;
      int row = idx >> 4, c4 = idx & 15;
      int gr = r0 + row;
      float4 v = make_float4(0.f, 0.f, 0.f, 0.f);
      if (gr < n) v = *(const float4*)(X + (size_t)gr * IN_DIM + kb * 64 + c4 * 4);
      xs[(c4 * 4 + 0) * SX + row] = v.x;
      xs[(c4 * 4 + 1) * SX + row] = v.y;
      xs[(c4 * 4 + 2) * SX + row] = v.z;
      xs[(c4 * 4 + 3) * SX + row] = v.w;
    }
    // stage W tile 64 k x 64 cols
    #pragma unroll
    for (int p = 0; p < 4; p++){
      int idx = p * 256 + tid;
      int k = idx >> 4, c4 = idx & 15;
      *(float4*)(ws + k * 64 + c4 * 4) = *(const float4*)(W + (size_t)(kb * 64 + k) * 64 + c4 * 4);
    }
    __syncthreads();
    #pragma unroll 4
    for (int k = 0; k < 64; k++){
      float4 x4 = *(const float4*)(xs + k * SX + tr * 4);
      float4 w4 = *(const float4*)(ws + k * 64 + tc * 4);
      float xv[4] = {x4.x, x4.y, x4.z, x4.w};
      float wv[4] = {w4.x, w4.y, w4.z, w4.w};
      #pragma unroll
      for (int i = 0; i < 4; i++)
        #pragma unroll
        for (int j = 0; j < 4; j++) acc[i][j] = fmaf(xv[i], wv[j], acc[i][j]);
    }
  }

  // epilogue: per-row scores (reduce over the 16 col-threads) + store H
  float av[4], bv[4];
  #pragma unroll
  for (int j = 0; j < 4; j++){ av[j] = a[tc * 4 + j]; bv[j] = a[64 + tc * 4 + j]; }
  float sp[4], dp[4];
  #pragma unroll
  for (int i = 0; i < 4; i++){
    float s = 0.f, d = 0.f;
    #pragma unroll
    for (int j = 0; j < 4; j++){ s = fmaf(acc[i][j], av[j], s); d = fmaf(acc[i][j], bv[j], d); }
    sp[i] = s; dp[i] = d;
  }
  #pragma unroll
  for (int off = 1; off < 16; off <<= 1){
    #pragma unroll
    for (int i = 0; i < 4; i++){
      sp[i] += __shfl_xor(sp[i], off, 16);
      dp[i] += __shfl_xor(dp[i], off, 16);
    }
  }
  #pragma unroll
  for (int i = 0; i < 4; i++){
    int r = r0 + tr * 4 + i;
    if (r < n){
      *(float4*)(H + (size_t)r * 64 + tc * 4) = make_float4(acc[i][0], acc[i][1], acc[i][2], acc[i][3]);
      if (tc == 0){ svec[r] = sp[i]; dvec[r] = dp[i]; }
    }
  }
}

// ---------------- GEMM 2: hid[N,64] @ W2[64,32] -> H2, s, d ----------------
// block = 64 rows x 32 cols, thread owns 4x2. tr = tid>>4, tc = tid&15 -> cols tc*2..+1

__global__ __launch_bounds__(256) void gemm2_kernel(const float* __restrict__ X, const float* __restrict__ W,
      const float* __restrict__ a, float* __restrict__ H,
      float* __restrict__ svec, float* __restrict__ dvec, int n){
  __shared__ float xs[64 * SX];   // [k][row]
  __shared__ float ws[64 * 32];   // [k][col]
  int tid = threadIdx.x;
  int r0 = blockIdx.x * 64;
  int tr = tid >> 4;
  int tc = tid & 15;
  float acc[4][2];
  #pragma unroll
  for (int i = 0; i < 4; i++){ acc[i][0] = 0.f; acc[i][1] = 0.f; }

  // stage X tile 64 rows x 64 k (whole K), transposed
  #pragma unroll
  for (int p = 0; p < 4; p++){
    int idx = p * 256 + tid;
    int row = idx >> 4, c4 = idx & 15;
    int gr = r0 + row;
    float4 v = make_float4(0.f, 0.f, 0.f, 0.f);
    if (gr < n) v = *(const float4*)(X + (size_t)gr * HID + c4 * 4);
    xs[(c4 * 4 + 0) * SX + row] = v.x;
    xs[(c4 * 4 + 1) * SX + row] = v.y;
    xs[(c4 * 4 + 2) * SX + row] = v.z;
    xs[(c4 * 4 + 3) * SX + row] = v.w;
  }
  // stage W 64 k x 32 cols
  #pragma unroll
  for (int p = 0; p < 2; p++){
    int idx = p * 256 + tid;
    int k = idx >> 3, c4 = idx & 7;
    *(float4*)(ws + k * 32 + c4 * 4) = *(const float4*)(W + (size_t)k * 32 + c4 * 4);
  }
  __syncthreads();
  #pragma unroll 4
  for (int k = 0; k < 64; k++){
    float4 x4 = *(const float4*)(xs + k * SX + tr * 4);
    float2 w2 = *(const float2*)(ws + k * 32 + tc * 2);
    float xv[4] = {x4.x, x4.y, x4.z, x4.w};
    #pragma unroll
    for (int i = 0; i < 4; i++){
      acc[i][0] = fmaf(xv[i], w2.x, acc[i][0]);
      acc[i][1] = fmaf(xv[i], w2.y, acc[i][1]);
    }
  }

  float a0 = a[tc * 2], a1 = a[tc * 2 + 1];
  float b0 = a[32 + tc * 2], b1 = a[32 + tc * 2 + 1];
  float sp[4], dp[4];
  #pragma unroll
  for (int i = 0; i < 4; i++){
    sp[i] = fmaf(acc[i][0], a0, acc[i][1] * a1);
    dp[i] = fmaf(acc[i][0], b0, acc[i][1] * b1);
  }
  #pragma unroll
  for (int off = 1; off < 16; off <<= 1){
    #pragma unroll
    for (int i = 0; i < 4; i++){
      sp[i] += __shfl_xor(sp[i], off, 16);
      dp[i] += __shfl_xor(dp[i], off, 16);
    }
  }
  #pragma unroll
  for (int i = 0; i < 4; i++){
    int r = r0 + tr * 4 + i;
    if (r < n){
      *(float2*)(H + (size_t)r * NC + tc * 2) = make_float2(acc[i][0], acc[i][1]);
      if (tc == 0){ svec[r] = sp[i]; dvec[r] = dp[i]; }
    }
  }
}

// ---------------- Aggregate layer 1: online softmax + ELU, D=64, 16 lanes/node ----------------

__global__ __launch_bounds__(256) void agg1_kernel(const float* __restrict__ H, const float* __restrict__ sv,
      const float* __restrict__ dv, const int* __restrict__ row_ptr, const int* __restrict__ csr,
      float* __restrict__ out, int n){
  int t = blockIdx.x * 256 + threadIdx.x;
  int g = t >> 4, lane = t & 15;
  if (g >= n) return;
  int beg = row_ptr[g], end = row_ptr[g + 1];
  float si = sv[g];
  float m = INF_NEG, l = 0.f;
  float ox = 0.f, oy = 0.f, oz = 0.f, ow = 0.f;
  for (int e = beg; e < end; e++){
    int dd = csr[e];
    float ev = lrelu(si + dv[dd]);
    float mn = fmaxf(m, ev);
    float al = __expf(m - mn);
    float w  = __expf(ev - mn);
    float4 v = *(const float4*)(H + (size_t)dd * 64 + lane * 4);
    ox = ox * al + w * v.x; oy = oy * al + w * v.y;
    oz = oz * al + w * v.z; ow = ow * al + w * v.w;
    l = l * al + w;
    m = mn;
  }
  float inv = (l > 0.f) ? 1.f / l : 0.f;
  ox *= inv; oy *= inv; oz *= inv; ow *= inv;
  ox = ox > 0.f ? ox : __expf(ox) - 1.f;
  oy = oy > 0.f ? oy : __expf(oy) - 1.f;
  oz = oz > 0.f ? oz : __expf(oz) - 1.f;
  ow = ow > 0.f ? ow : __expf(ow) - 1.f;
  *(float4*)(out + (size_t)g * 64 + lane * 4) = make_float4(ox, oy, oz, ow);
}

// ---------------- Aggregate layer 2: online softmax + log_softmax, D=32, 8 lanes/node ----------------

__global__ __launch_bounds__(256) void agg2_kernel(const float* __restrict__ H, const float* __restrict__ sv,
      const float* __restrict__ dv, const int* __restrict__ row_ptr, const int* __restrict__ csr,
      float* __restrict__ out, int n){
  int t = blockIdx.x * 256 + threadIdx.x;
  int g = t >> 3, lane = t & 7;
  if (g >= n) return;
  int beg = row_ptr[g], end = row_ptr[g + 1];
  float si = sv[g];
  float m = INF_NEG, l = 0.f;
  float ox = 0.f, oy = 0.f, oz = 0.f, ow = 0.f;
  for (int e = beg; e < end; e++){
    int dd = csr[e];
    float ev = lrelu(si + dv[dd]);
    float mn = fmaxf(m, ev);
    float al = __expf(m - mn);
    float w  = __expf(ev - mn);
    float4 v = *(const float4*)(H + (size_t)dd * 32 + lane * 4);
    ox = ox * al + w * v.x; oy = oy * al + w * v.y;
    oz = oz * al + w * v.z; ow = ow * al + w * v.w;
    l = l * al + w;
    m = mn;
  }
  float inv = (l > 0.f) ? 1.f / l : 0.f;
  ox *= inv; oy *= inv; oz *= inv; ow *= inv;
  float tm = fmaxf(fmaxf(ox, oy), fmaxf(oz, ow));
  #pragma unroll
  for (int off = 1; off < 8; off <<= 1) tm = fmaxf(tm, __shfl_xor(tm, off, 8));
  float se = __expf(ox - tm) + __expf(oy - tm) + __expf(oz - tm) + __expf(ow - tm);
  #pragma unroll
  for (int off = 1; off < 8; off <<= 1) se += __shfl_xor(se, off, 8);
  float lg = tm + __logf(se);
  *(float4*)(out + (size_t)g * 32 + lane * 4) = make_float4(ox - lg, oy - lg, oz - lg, ow - lg);
}

// ---------------- launch ----------------

extern "C" void kernel_launch(void* const* d_in, const int* in_sizes, int n_in,
                              void* d_out, int out_size, void* d_ws, size_t ws_size,
                              hipStream_t stream) {
  (void)n_in; (void)out_size; (void)ws_size;
  const float* X  = (const float*)d_in[0];
  const int*   EI = (const int*)d_in[1];
  const float* W1 = (const float*)d_in[2];
  const float* W2 = (const float*)d_in[3];
  const float* A1 = (const float*)d_in[4];
  const float* A2 = (const float*)d_in[5];
  float* out = (float*)d_out;

  int N = in_sizes[0] / IN_DIM;
  int E = in_sizes[1] / 2;
  const int* src = EI;
  const int* dst = EI + E;

  auto align_up = [](size_t x){ return (x + 511) & ~(size_t)511; };
  char* w = (char*)d_ws;
  int* counts  = (int*)w;   w += align_up((size_t)N * 4);
  int* fill    = (int*)w;   w += align_up((size_t)N * 4);
  int* row_ptr = (int*)w;   w += align_up((size_t)(N + 1) * 4);
  int* bsums   = (int*)w;   w += align_up(1024);
  int* csr     = (int*)w;   w += align_up((size_t)E * 4);
  float* H1    = (float*)w; w += align_up((size_t)N * 64 * 4);
  float* hid   = (float*)w; w += align_up((size_t)N * 64 * 4);
  float* s1    = (float*)w; w += align_up((size_t)N * 4);
  float* d1    = (float*)w; w += align_up((size_t)N * 4);
  float* s2    = (float*)w; w += align_up((size_t)N * 4);
  float* d2    = (float*)w; w += align_up((size_t)N * 4);
  float* H2    = H1;  // H1 dead after agg1; reuse

  hipMemsetAsync(counts, 0, (size_t)N * 4, stream);
  hipMemsetAsync(fill,   0, (size_t)N * 4, stream);

  int nb = ceil_div(N, 1024);
  hist_kernel<<<ceil_div(E, 256), 256, 0, stream>>>(src, counts, E);
  scan_blocks_kernel<<<nb, 256, 0, stream>>>(counts, row_ptr, bsums, N);
  scan_sums_kernel<<<1, 256, 0, stream>>>(bsums, row_ptr, nb, N, E);
  add_offsets_kernel<<<nb, 1024, 0, stream>>>(row_ptr, bsums, N);
  scatter_kernel<<<ceil_div(E, 256), 256, 0, stream>>>(src, dst, row_ptr, fill, csr, E);

  gemm1_kernel<<<ceil_div(N, 64), 256, 0, stream>>>(X, W1, A1, H1, s1, d1, N);
  agg1_kernel<<<ceil_div(N * 16, 256), 256, 0, stream>>>(H1, s1, d1, row_ptr, csr, hid, N);
  gemm2_kernel<<<ceil_div(N, 64), 256, 0, stream>>>(hid, W2, A2, H2, s2, d2, N);
  agg2_kernel<<<ceil_div(N * 8, 256), 256, 0, stream>>>(H2, s2, d2, row_ptr, csr, out, N);
}

// Round 3
// 441.324 us; speedup vs baseline: 1.2838x; 1.0763x over previous
//
#include <hip/hip_runtime.h>
#include <math.h>

#define IN_DIM 256
#define HID 64
#define NC 32
#define NEG 0.01f
#define INF_NEG -1e30f
#define SX 68       // LDS stride for transposed X tile (float4-aligned, 2-way conflicts only)
#define MAXNBK 512  // max buckets (N <= 131072 for 17-bit dst packing)
#define BCAP 12288  // bucket scatter LDS capacity (entries)

static inline int ceil_div(int a, int b){ return (a + b - 1) / b; }

static __device__ __forceinline__ float lrelu(float x){ return x > 0.f ? x : NEG * x; }

// ---------------- CSR build ----------------

__global__ void hist_kernel(const int* __restrict__ src, int* __restrict__ counts, int E){
  int i = blockIdx.x * blockDim.x + threadIdx.x;
  if (i < E) atomicAdd(&counts[src[i]], 1);
}

__global__ void scan_blocks_kernel(const int* __restrict__ counts, int* __restrict__ excl,
                                   int* __restrict__ bsums, int n){
  __shared__ int sh[256];
  int tid = threadIdx.x;
  int base = blockIdx.x * 1024 + tid * 4;
  int c[4]; int tsum = 0;
  #pragma unroll
  for (int j = 0; j < 4; j++){ int i = base + j; c[j] = (i < n) ? counts[i] : 0; tsum += c[j]; }
  sh[tid] = tsum; __syncthreads();
  int val = tsum;
  for (int off = 1; off < 256; off <<= 1){
    int add = (tid >= off) ? sh[tid - off] : 0;
    __syncthreads();
    val += add; sh[tid] = val;
    __syncthreads();
  }
  int p = val - tsum;
  #pragma unroll
  for (int j = 0; j < 4; j++){ int i = base + j; if (i < n) excl[i] = p; p += c[j]; }
  if (tid == 255) bsums[blockIdx.x] = val;
}

__global__ void scan_sums_kernel(int* __restrict__ bsums, int* __restrict__ row_ptr,
                                 int nb, int n, int E){
  __shared__ int sh[256];
  int tid = threadIdx.x;
  int v = (tid < nb) ? bsums[tid] : 0;
  sh[tid] = v; __syncthreads();
  int val = v;
  for (int off = 1; off < 256; off <<= 1){
    int add = (tid >= off) ? sh[tid - off] : 0;
    __syncthreads();
    val += add; sh[tid] = val;
    __syncthreads();
  }
  if (tid < nb) bsums[tid] = val - v;
  if (tid == 0) row_ptr[n] = E;
}

__global__ void add_offsets_kernel(int* __restrict__ excl, const int* __restrict__ bsums, int n){
  int i = blockIdx.x * 1024 + threadIdx.x;
  if (i < n) excl[i] += bsums[blockIdx.x];
}

// fallback only (N > 2^17): the old random scatter
__global__ void scatter_kernel(const int* __restrict__ src, const int* __restrict__ dst,
                               const int* __restrict__ row_ptr, int* __restrict__ fill,
                               int* __restrict__ csr, int E){
  int i = blockIdx.x * blockDim.x + threadIdx.x;
  if (i >= E) return;
  int s = src[i];
  int pos = row_ptr[s] + atomicAdd(&fill[s], 1);
  csr[pos] = dst[i];
}

__global__ void init_cursor_kernel(const int* __restrict__ row_ptr, int* __restrict__ cursor,
                                   int nbk, int n){
  int b = blockIdx.x * 256 + threadIdx.x;
  if (b < nbk) cursor[b] = row_ptr[min(b << 8, n)];
}

// Phase A: bucket edges by src>>8 into tmp (laid out like final csr).
// Entry = (src & 255) << 17 | dst. Per-block LDS histogram -> contiguous run reservations.
__global__ __launch_bounds__(256) void bin_kernel(const int* __restrict__ src,
      const int* __restrict__ dst, int* __restrict__ cursor,
      unsigned int* __restrict__ tmp, int E, int nbk){
  __shared__ int hist[MAXNBK];
  __shared__ int base[MAXNBK];
  int nb = gridDim.x;
  int per = (E + nb - 1) / nb;
  int beg = blockIdx.x * per;
  int end = min(E, beg + per);
  for (int i = threadIdx.x; i < nbk; i += 256) hist[i] = 0;
  __syncthreads();
  for (int e = beg + threadIdx.x; e < end; e += 256)
    atomicAdd(&hist[src[e] >> 8], 1);
  __syncthreads();
  for (int i = threadIdx.x; i < nbk; i += 256){
    int c = hist[i];
    base[i] = (c > 0) ? atomicAdd(&cursor[i], c) : 0;
    hist[i] = 0;   // reuse as local rank counter
  }
  __syncthreads();
  for (int e = beg + threadIdx.x; e < end; e += 256){
    int s = src[e];
    int b = s >> 8;
    int r = atomicAdd(&hist[b], 1);
    tmp[base[b] + r] = ((unsigned)(s & 255) << 17) | (unsigned)dst[e];
  }
}

// Phase B: one block per bucket; scatter bucket entries to exact CSR positions in LDS,
// then write the segment out coalesced.
__global__ __launch_bounds__(256) void bucket_scatter_kernel(const unsigned int* __restrict__ tmp,
      const int* __restrict__ row_ptr, int* __restrict__ csr, int n){
  __shared__ int cur[256];
  __shared__ int lbuf[BCAP];
  int b = blockIdx.x;
  int n0 = b << 8;
  int nn = min(256, n - n0);
  int segb = row_ptr[n0];
  int sege = row_ptr[n0 + nn];
  int len = sege - segb;
  for (int i = threadIdx.x; i < nn; i += 256) cur[i] = row_ptr[n0 + i] - segb;
  __syncthreads();
  if (len <= BCAP){
    for (int e = threadIdx.x; e < len; e += 256){
      unsigned v = tmp[segb + e];
      int pos = atomicAdd(&cur[v >> 17], 1);
      lbuf[pos] = (int)(v & 0x1FFFF);
    }
    __syncthreads();
    for (int e = threadIdx.x; e < len; e += 256) csr[segb + e] = lbuf[e];
  } else {
    for (int e = threadIdx.x; e < len; e += 256){
      unsigned v = tmp[segb + e];
      int pos = atomicAdd(&cur[v >> 17], 1);
      csr[segb + pos] = (int)(v & 0x1FFFF);
    }
  }
}

// ---------------- GEMM 1: X[N,256] @ W1[256,64] -> H, s, d ----------------

__global__ __launch_bounds__(256) void gemm1_kernel(const float* __restrict__ X, const float* __restrict__ W,
      const float* __restrict__ a, float* __restrict__ H,
      float* __restrict__ svec, float* __restrict__ dvec, int n){
  __shared__ float xs[64 * SX];   // [k][row] transposed
  __shared__ float ws[64 * 64];   // [k][col]
  int tid = threadIdx.x;
  int r0 = blockIdx.x * 64;
  int tr = tid >> 4;
  int tc = tid & 15;
  float acc[4][4];
  #pragma unroll
  for (int i = 0; i < 4; i++)
    #pragma unroll
    for (int j = 0; j < 4; j++) acc[i][j] = 0.f;

  for (int kb = 0; kb < 4; kb++){
    __syncthreads();
    #pragma unroll
    for (int p = 0; p < 4; p++){
      int idx = p * 256 + tid;
      int row = idx >> 4, c4 = idx & 15;
      int gr = r0 + row;
      float4 v = make_float4(0.f, 0.f, 0.f, 0.f);
      if (gr < n) v = *(const float4*)(X + (size_t)gr * IN_DIM + kb * 64 + c4 * 4);
      xs[(c4 * 4 + 0) * SX + row] = v.x;
      xs[(c4 * 4 + 1) * SX + row] = v.y;
      xs[(c4 * 4 + 2) * SX + row] = v.z;
      xs[(c4 * 4 + 3) * SX + row] = v.w;
    }
    #pragma unroll
    for (int p = 0; p < 4; p++){
      int idx = p * 256 + tid;
      int k = idx >> 4, c4 = idx & 15;
      *(float4*)(ws + k * 64 + c4 * 4) = *(const float4*)(W + (size_t)(kb * 64 + k) * 64 + c4 * 4);
    }
    __syncthreads();
    #pragma unroll 4
    for (int k = 0; k < 64; k++){
      float4 x4 = *(const float4*)(xs + k * SX + tr * 4);
      float4 w4 = *(const float4*)(ws + k * 64 + tc * 4);
      float xv[4] = {x4.x, x4.y, x4.z, x4.w};
      float wv[4] = {w4.x, w4.y, w4.z, w4.w};
      #pragma unroll
      for (int i = 0; i < 4; i++)
        #pragma unroll
        for (int j = 0; j < 4; j++) acc[i][j] = fmaf(xv[i], wv[j], acc[i][j]);
    }
  }

  float av[4], bv[4];
  #pragma unroll
  for (int j = 0; j < 4; j++){ av[j] = a[tc * 4 + j]; bv[j] = a[64 + tc * 4 + j]; }
  float sp[4], dp[4];
  #pragma unroll
  for (int i = 0; i < 4; i++){
    float s = 0.f, d = 0.f;
    #pragma unroll
    for (int j = 0; j < 4; j++){ s = fmaf(acc[i][j], av[j], s); d = fmaf(acc[i][j], bv[j], d); }
    sp[i] = s; dp[i] = d;
  }
  #pragma unroll
  for (int off = 1; off < 16; off <<= 1){
    #pragma unroll
    for (int i = 0; i < 4; i++){
      sp[i] += __shfl_xor(sp[i], off, 16);
      dp[i] += __shfl_xor(dp[i], off, 16);
    }
  }
  #pragma unroll
  for (int i = 0; i < 4; i++){
    int r = r0 + tr * 4 + i;
    if (r < n){
      *(float4*)(H + (size_t)r * 64 + tc * 4) = make_float4(acc[i][0], acc[i][1], acc[i][2], acc[i][3]);
      if (tc == 0){ svec[r] = sp[i]; dvec[r] = dp[i]; }
    }
  }
}

// ---------------- GEMM 2: hid[N,64] @ W2[64,32] -> H2, s, d ----------------

__global__ __launch_bounds__(256) void gemm2_kernel(const float* __restrict__ X, const float* __restrict__ W,
      const float* __restrict__ a, float* __restrict__ H,
      float* __restrict__ svec, float* __restrict__ dvec, int n){
  __shared__ float xs[64 * SX];
  __shared__ float ws[64 * 32];
  int tid = threadIdx.x;
  int r0 = blockIdx.x * 64;
  int tr = tid >> 4;
  int tc = tid & 15;
  float acc[4][2];
  #pragma unroll
  for (int i = 0; i < 4; i++){ acc[i][0] = 0.f; acc[i][1] = 0.f; }

  #pragma unroll
  for (int p = 0; p < 4; p++){
    int idx = p * 256 + tid;
    int row = idx >> 4, c4 = idx & 15;
    int gr = r0 + row;
    float4 v = make_float4(0.f, 0.f, 0.f, 0.f);
    if (gr < n) v = *(const float4*)(X + (size_t)gr * HID + c4 * 4);
    xs[(c4 * 4 + 0) * SX + row] = v.x;
    xs[(c4 * 4 + 1) * SX + row] = v.y;
    xs[(c4 * 4 + 2) * SX + row] = v.z;
    xs[(c4 * 4 + 3) * SX + row] = v.w;
  }
  #pragma unroll
  for (int p = 0; p < 2; p++){
    int idx = p * 256 + tid;
    int k = idx >> 3, c4 = idx & 7;
    *(float4*)(ws + k * 32 + c4 * 4) = *(const float4*)(W + (size_t)k * 32 + c4 * 4);
  }
  __syncthreads();
  #pragma unroll 4
  for (int k = 0; k < 64; k++){
    float4 x4 = *(const float4*)(xs + k * SX + tr * 4);
    float2 w2 = *(const float2*)(ws + k * 32 + tc * 2);
    float xv[4] = {x4.x, x4.y, x4.z, x4.w};
    #pragma unroll
    for (int i = 0; i < 4; i++){
      acc[i][0] = fmaf(xv[i], w2.x, acc[i][0]);
      acc[i][1] = fmaf(xv[i], w2.y, acc[i][1]);
    }
  }

  float a0 = a[tc * 2], a1 = a[tc * 2 + 1];
  float b0 = a[32 + tc * 2], b1 = a[32 + tc * 2 + 1];
  float sp[4], dp[4];
  #pragma unroll
  for (int i = 0; i < 4; i++){
    sp[i] = fmaf(acc[i][0], a0, acc[i][1] * a1);
    dp[i] = fmaf(acc[i][0], b0, acc[i][1] * b1);
  }
  #pragma unroll
  for (int off = 1; off < 16; off <<= 1){
    #pragma unroll
    for (int i = 0; i < 4; i++){
      sp[i] += __shfl_xor(sp[i], off, 16);
      dp[i] += __shfl_xor(dp[i], off, 16);
    }
  }
  #pragma unroll
  for (int i = 0; i < 4; i++){
    int r = r0 + tr * 4 + i;
    if (r < n){
      *(float2*)(H + (size_t)r * NC + tc * 2) = make_float2(acc[i][0], acc[i][1]);
      if (tc == 0){ svec[r] = sp[i]; dvec[r] = dp[i]; }
    }
  }
}

// ---------------- Aggregate layer 1: online softmax + ELU, D=64, 16 lanes/node ----------------

__global__ __launch_bounds__(256) void agg1_kernel(const float* __restrict__ H, const float* __restrict__ sv,
      const float* __restrict__ dv, const int* __restrict__ row_ptr, const int* __restrict__ csr,
      float* __restrict__ out, int n){
  int t = blockIdx.x * 256 + threadIdx.x;
  int g = t >> 4, lane = t & 15;
  if (g >= n) return;
  int beg = row_ptr[g], end = row_ptr[g + 1];
  float si = sv[g];
  float m = INF_NEG, l = 0.f;
  float ox = 0.f, oy = 0.f, oz = 0.f, ow = 0.f;
  for (int e = beg; e < end; e++){
    int dd = csr[e];
    float ev = lrelu(si + dv[dd]);
    float mn = fmaxf(m, ev);
    float al = __expf(m - mn);
    float w  = __expf(ev - mn);
    float4 v = *(const float4*)(H + (size_t)dd * 64 + lane * 4);
    ox = ox * al + w * v.x; oy = oy * al + w * v.y;
    oz = oz * al + w * v.z; ow = ow * al + w * v.w;
    l = l * al + w;
    m = mn;
  }
  float inv = (l > 0.f) ? 1.f / l : 0.f;
  ox *= inv; oy *= inv; oz *= inv; ow *= inv;
  ox = ox > 0.f ? ox : __expf(ox) - 1.f;
  oy = oy > 0.f ? oy : __expf(oy) - 1.f;
  oz = oz > 0.f ? oz : __expf(oz) - 1.f;
  ow = ow > 0.f ? ow : __expf(ow) - 1.f;
  *(float4*)(out + (size_t)g * 64 + lane * 4) = make_float4(ox, oy, oz, ow);
}

// ---------------- Aggregate layer 2: online softmax + log_softmax, D=32, 8 lanes/node ----------------

__global__ __launch_bounds__(256) void agg2_kernel(const float* __restrict__ H, const float* __restrict__ sv,
      const float* __restrict__ dv, const int* __restrict__ row_ptr, const int* __restrict__ csr,
      float* __restrict__ out, int n){
  int t = blockIdx.x * 256 + threadIdx.x;
  int g = t >> 3, lane = t & 7;
  if (g >= n) return;
  int beg = row_ptr[g], end = row_ptr[g + 1];
  float si = sv[g];
  float m = INF_NEG, l = 0.f;
  float ox = 0.f, oy = 0.f, oz = 0.f, ow = 0.f;
  for (int e = beg; e < end; e++){
    int dd = csr[e];
    float ev = lrelu(si + dv[dd]);
    float mn = fmaxf(m, ev);
    float al = __expf(m - mn);
    float w  = __expf(ev - mn);
    float4 v = *(const float4*)(H + (size_t)dd * 32 + lane * 4);
    ox = ox * al + w * v.x; oy = oy * al + w * v.y;
    oz = oz * al + w * v.z; ow = ow * al + w * v.w;
    l = l * al + w;
    m = mn;
  }
  float inv = (l > 0.f) ? 1.f / l : 0.f;
  ox *= inv; oy *= inv; oz *= inv; ow *= inv;
  float tm = fmaxf(fmaxf(ox, oy), fmaxf(oz, ow));
  #pragma unroll
  for (int off = 1; off < 8; off <<= 1) tm = fmaxf(tm, __shfl_xor(tm, off, 8));
  float se = __expf(ox - tm) + __expf(oy - tm) + __expf(oz - tm) + __expf(ow - tm);
  #pragma unroll
  for (int off = 1; off < 8; off <<= 1) se += __shfl_xor(se, off, 8);
  float lg = tm + __logf(se);
  *(float4*)(out + (size_t)g * 32 + lane * 4) = make_float4(ox - lg, oy - lg, oz - lg, ow - lg);
}

// ---------------- launch ----------------

extern "C" void kernel_launch(void* const* d_in, const int* in_sizes, int n_in,
                              void* d_out, int out_size, void* d_ws, size_t ws_size,
                              hipStream_t stream) {
  (void)n_in; (void)out_size; (void)ws_size;
  const float* X  = (const float*)d_in[0];
  const int*   EI = (const int*)d_in[1];
  const float* W1 = (const float*)d_in[2];
  const float* W2 = (const float*)d_in[3];
  const float* A1 = (const float*)d_in[4];
  const float* A2 = (const float*)d_in[5];
  float* out = (float*)d_out;

  int N = in_sizes[0] / IN_DIM;
  int E = in_sizes[1] / 2;
  const int* src = EI;
  const int* dst = EI + E;

  auto align_up = [](size_t x){ return (x + 511) & ~(size_t)511; };
  char* w = (char*)d_ws;
  int* counts  = (int*)w;   w += align_up((size_t)N * 4);
  int* cursor  = (int*)w;   w += align_up((size_t)MAXNBK * 4);   // bucket cursors (or fill[] in fallback)
  int* row_ptr = (int*)w;   w += align_up((size_t)(N + 1) * 4);
  int* bsums   = (int*)w;   w += align_up(1024);
  int* csr     = (int*)w;   w += align_up((size_t)E * 4);
  float* H1    = (float*)w; w += align_up((size_t)N * 64 * 4);
  float* hid   = (float*)w; w += align_up((size_t)N * 64 * 4);
  float* s1    = (float*)w; w += align_up((size_t)N * 4);
  float* d1    = (float*)w; w += align_up((size_t)N * 4);
  float* s2    = (float*)w; w += align_up((size_t)N * 4);
  float* d2    = (float*)w; w += align_up((size_t)N * 4);
  float* H2    = H1;                    // H1 dead after agg1; reuse
  unsigned int* tmp = (unsigned int*)hid;   // hid dead until agg1; binned edges alias it

  hipMemsetAsync(counts, 0, (size_t)N * 4, stream);

  int nb = ceil_div(N, 1024);
  int nbk = ceil_div(N, 256);
  hist_kernel<<<ceil_div(E, 256), 256, 0, stream>>>(src, counts, E);
  scan_blocks_kernel<<<nb, 256, 0, stream>>>(counts, row_ptr, bsums, N);
  scan_sums_kernel<<<1, 256, 0, stream>>>(bsums, row_ptr, nb, N, E);
  add_offsets_kernel<<<nb, 1024, 0, stream>>>(row_ptr, bsums, N);

  if (N <= (1 << 17) && nbk <= MAXNBK){
    init_cursor_kernel<<<ceil_div(nbk, 256), 256, 0, stream>>>(row_ptr, cursor, nbk, N);
    bin_kernel<<<256, 256, 0, stream>>>(src, dst, cursor, tmp, E, nbk);
    bucket_scatter_kernel<<<nbk, 256, 0, stream>>>(tmp, row_ptr, csr, N);
  } else {
    // fallback: cursor doubles as fill[] — but needs N ints; only valid when N fits MAXNBK path.
    hipMemsetAsync(counts, 0, (size_t)N * 4, stream);  // reuse counts as fill
    scatter_kernel<<<ceil_div(E, 256), 256, 0, stream>>>(src, dst, row_ptr, counts, csr, E);
  }

  gemm1_kernel<<<ceil_div(N, 64), 256, 0, stream>>>(X, W1, A1, H1, s1, d1, N);
  agg1_kernel<<<ceil_div(N * 16, 256), 256, 0, stream>>>(H1, s1, d1, row_ptr, csr, hid, N);
  gemm2_kernel<<<ceil_div(N, 64), 256, 0, stream>>>(hid, W2, A2, H2, s2, d2, N);
  agg2_kernel<<<ceil_div(N * 8, 256), 256, 0, stream>>>(H2, s2, d2, row_ptr, csr, out, N);
}